// Round 3
// baseline (307.921 us; speedup 1.0000x reference)
//
#include <hip/hip_runtime.h>
#include <math.h>

#define V   50000
#define DIM 128
#define BB  512
#define LQ  30
#define RD  200
#define KN  21
#define CG  7     // col groups of 32 (224 >= 200)

typedef unsigned short ushort_t;
typedef __attribute__((ext_vector_type(8))) short bf16x8;   // 8 bf16 = 4 VGPRs
typedef __attribute__((ext_vector_type(4))) float f32x4;

#if __has_builtin(__builtin_amdgcn_exp2f)
#define EXP2F(x) __builtin_amdgcn_exp2f(x)
#else
#define EXP2F(x) __expf((x) * 0.69314718f)
#endif

static __device__ __forceinline__ ushort_t f2bf(float x) {
    unsigned u = __builtin_bit_cast(unsigned, x);
    return (ushort_t)((u + 0x7FFFu + ((u >> 16) & 1u)) >> 16);   // RNE
}
static __device__ __forceinline__ float bf2f(ushort_t h) {
    unsigned u = ((unsigned)h) << 16;
    return __builtin_bit_cast(float, u);
}
static __device__ __forceinline__ bf16x8 as_frag(int4 v) {
    return __builtin_bit_cast(bf16x8, v);
}

// ------------- kernel 1: normalize + split into hi/lo bf16 -------------
__global__ __launch_bounds__(256) void knrm_norm(const float* __restrict__ emb,
                                                 ushort_t* __restrict__ nh,
                                                 ushort_t* __restrict__ nl) {
    int row  = blockIdx.x * 4 + (threadIdx.x >> 6);
    int lane = threadIdx.x & 63;
    if (row >= V) return;
    const float2 v = *reinterpret_cast<const float2*>(emb + (size_t)row * DIM + lane * 2);
    float ss = v.x * v.x + v.y * v.y;
#pragma unroll
    for (int off = 32; off; off >>= 1) ss += __shfl_xor(ss, off);
    float inv = 1.0f / fmaxf(sqrtf(ss), 1e-12f);
    float x0 = v.x * inv, x1 = v.y * inv;
    ushort_t h0 = f2bf(x0), h1 = f2bf(x1);
    ushort_t l0 = f2bf(x0 - bf2f(h0)), l1 = f2bf(x1 - bf2f(h1));
    ushort2 ho; ho.x = h0; ho.y = h1;
    ushort2 lo; lo.x = l0; lo.y = l1;
    *reinterpret_cast<ushort2*>(nh + (size_t)row * DIM + lane * 2) = ho;
    *reinterpret_cast<ushort2*>(nl + (size_t)row * DIM + lane * 2) = lo;
}

// ------------- kernel 2: gather-direct MFMA + row-serial bank -------------
// grid (1024 pair*b, 7 colgroups), block 256 = 4 waves.
// wave = (rt = 16-row tile, sc = 16-col subtile). Frags gathered straight from
// global (L2/L3-resident tables) -> 12 MFMA -> P via 4.6KB LDS (1 barrier) ->
// bank with thread = (row, 4 cols): ksum[21] regs, 8-lane shuffle reduce,
// atomicAdd partials per (pair*b, row, k).
__global__ __launch_bounds__(256) void knrm_main(
    const ushort_t* __restrict__ nh, const ushort_t* __restrict__ nl,
    const int* __restrict__ q1, const int* __restrict__ d1,
    const int* __restrict__ q2, const int* __restrict__ d2,
    float* __restrict__ partial)
{
    __shared__ float P[32][36];   // stride 36: float4-aligned rows, spread banks

    const int pb = blockIdx.x, cg = blockIdx.y;
    const int pair = pb >> 9, b = pb & 511;
    const int* qind = (pair ? q2 : q1) + b * LQ;
    const int* dind = (pair ? d2 : d1) + b * RD;

    const int tid  = threadIdx.x;
    const int lane = tid & 63, wave = tid >> 6;
    const int rt = wave & 1, sc = wave >> 1;
    const int r = lane & 15, g = lane >> 4;

    const int qrow = rt * 16 + r;
    const int dcol = cg * 32 + sc * 16 + r;
    const int qi = qind[qrow < LQ ? qrow : LQ - 1];
    const int di = dind[dcol < RD ? dcol : RD - 1];

    const int4* qhp = (const int4*)(nh + (size_t)qi * DIM);
    const int4* qlp = (const int4*)(nl + (size_t)qi * DIM);
    const int4* dhp = (const int4*)(nh + (size_t)di * DIM);
    const int4* dlp = (const int4*)(nl + (size_t)di * DIM);

    // ---- M subtile: 3-split bf16 MFMA, frags direct from global ----
    f32x4 acc = {0.f, 0.f, 0.f, 0.f};
#pragma unroll
    for (int ks = 0; ks < 4; ++ks) {
        const int off = ks * 4 + g;             // int4 slot within the 128-dim row
        bf16x8 ah = as_frag(qhp[off]);
        bf16x8 al = as_frag(qlp[off]);
        bf16x8 bh = as_frag(dhp[off]);
        bf16x8 bl = as_frag(dlp[off]);
        acc = __builtin_amdgcn_mfma_f32_16x16x32_bf16(ah, bh, acc, 0, 0, 0);
        acc = __builtin_amdgcn_mfma_f32_16x16x32_bf16(ah, bl, acc, 0, 0, 0);
        acc = __builtin_amdgcn_mfma_f32_16x16x32_bf16(al, bh, acc, 0, 0, 0);
    }

    // C/D layout: col = lane&15, row = (lane>>4)*4 + j  (m89/m91 verified)
#pragma unroll
    for (int j = 0; j < 4; ++j)
        P[rt * 16 + g * 4 + j][sc * 16 + r] = acc[j];
    __syncthreads();

    // ---- bank phase: thread t -> row t>>3, cols (t&7)*4 .. +3 ----
    const int row = tid >> 3;
    const int c0 = (tid & 7) * 4;
    const float4 pv = *reinterpret_cast<const float4*>(&P[row][c0]);

    float ksum[KN];
#pragma unroll
    for (int k = 0; k < KN; ++k) ksum[k] = 0.0f;

#pragma unroll
    for (int i = 0; i < 4; ++i) {
        const int col = cg * 32 + c0 + i;
        float m = (row < LQ && col < RD) ? ((const float*)&pv)[i] : 16.0f;
        float t0 = m + 0.95f;
        float e0 = (-72.134752f * t0) * t0;               // -50*log2e*t0^2
        float de = fmaf(14.4269504f, t0, -0.72134752f);
#pragma unroll
        for (int k = 0; k < 20; ++k) {
            ksum[k] += EXP2F(e0);
            e0 += de;
            de -= 1.4426950f;
        }
        float t = m - 1.0f;                                // exact kernel (sigma=1e-3)
        ksum[20] += EXP2F((-721347.52f * t) * t);
    }

    // reduce over the 8 threads sharing a row (lane bits 0..2)
#pragma unroll
    for (int k = 0; k < KN; ++k) {
        float v = ksum[k];
        v += __shfl_xor(v, 1);
        v += __shfl_xor(v, 2);
        v += __shfl_xor(v, 4);
        ksum[k] = v;
    }
    if ((tid & 7) == 0 && row < LQ) {
        float* dst = partial + ((size_t)pb * 32 + row) * KN;
#pragma unroll
        for (int k = 0; k < KN; ++k) atomicAdd(dst + k, ksum[k]);
    }
}

// ------------- kernel 3: log1p, W-dot, pair difference, sigmoid -------------
__global__ __launch_bounds__(128) void knrm_finish(const float* __restrict__ partial,
                                                   const float* __restrict__ W,
                                                   float* __restrict__ out) {
    __shared__ float red[2];
    const int b = blockIdx.x, tid = threadIdx.x;
    float s = 0.0f;
    for (int e = tid; e < LQ * KN; e += 128) {
        int row = e / KN, k = e - row * KN;
        float s1 = partial[((size_t)b * 32 + row) * KN + k];
        float s2 = partial[((size_t)(BB + b) * 32 + row) * KN + k];
        s += W[k] * (log1pf(s1) - log1pf(s2));
    }
    s += __shfl_xor(s, 1);  s += __shfl_xor(s, 2);  s += __shfl_xor(s, 4);
    s += __shfl_xor(s, 8);  s += __shfl_xor(s, 16); s += __shfl_xor(s, 32);
    if ((tid & 63) == 0) red[tid >> 6] = s;
    __syncthreads();
    if (tid == 0) {
        float logit = red[0] + red[1];   // bias cancels in the difference
        out[b] = 1.0f / (1.0f + expf(-logit));
    }
}

extern "C" void kernel_launch(void* const* d_in, const int* in_sizes, int n_in,
                              void* d_out, int out_size, void* d_ws, size_t ws_size,
                              hipStream_t stream) {
    const float* emb = (const float*)d_in[0];
    const float* W   = (const float*)d_in[1];
    const int* q1    = (const int*)d_in[3];
    const int* dd1   = (const int*)d_in[4];
    const int* q2    = (const int*)d_in[5];
    const int* dd2   = (const int*)d_in[6];

    float* partial = (float*)d_ws;                       // 1024*32*21 f32 = 2.75 MB
    ushort_t* nh   = (ushort_t*)(partial + 1024 * 32 * KN);
    ushort_t* nl   = nh + (size_t)V * DIM;               // 12.8 MB each

    hipMemsetAsync(partial, 0, (size_t)1024 * 32 * KN * sizeof(float), stream);
    knrm_norm<<<(V + 3) / 4, 256, 0, stream>>>(emb, nh, nl);
    dim3 grid(1024, CG);
    knrm_main<<<grid, 256, 0, stream>>>(nh, nl, q1, dd1, q2, dd2, partial);
    knrm_finish<<<BB, 128, 0, stream>>>(partial, W, (float*)d_out);
}

// Round 4
// 62.741 us; speedup vs baseline: 4.9078x; 4.9078x over previous
//
#include <hip/hip_runtime.h>
#include <math.h>

#define V   50000
#define DIM 128
#define BB  512
#define LQ  30
#define RD  200
#define KN  21
#define NT  4      // 4 doc tiles of 64 cols (256 >= 200)

typedef unsigned short ushort_t;
typedef __attribute__((ext_vector_type(8))) short bf16x8;   // 8 bf16 = 4 VGPRs
typedef __attribute__((ext_vector_type(4))) float f32x4;

#if __has_builtin(__builtin_amdgcn_exp2f)
#define EXP2F(x) __builtin_amdgcn_exp2f(x)
#else
#define EXP2F(x) __expf((x) * 0.69314718f)
#endif

static __device__ __forceinline__ ushort_t f2bf(float x) {
    unsigned u = __builtin_bit_cast(unsigned, x);
    return (ushort_t)((u + 0x7FFFu + ((u >> 16) & 1u)) >> 16);   // RNE
}
static __device__ __forceinline__ bf16x8 as_frag(int4 v) {
    return __builtin_bit_cast(bf16x8, v);
}

// ------------- kernel 1: L2-normalize -> bf16 (hi only) -------------
__global__ __launch_bounds__(256) void knrm_norm(const float* __restrict__ emb,
                                                 ushort_t* __restrict__ nh) {
    int row  = blockIdx.x * 4 + (threadIdx.x >> 6);   // V divisible by 4
    int lane = threadIdx.x & 63;
    const float2 v = *reinterpret_cast<const float2*>(emb + (size_t)row * DIM + lane * 2);
    float ss = v.x * v.x + v.y * v.y;
#pragma unroll
    for (int off = 32; off; off >>= 1) ss += __shfl_xor(ss, off);
    float inv = 1.0f / fmaxf(sqrtf(ss), 1e-12f);
    ushort2 o;
    o.x = f2bf(v.x * inv);
    o.y = f2bf(v.y * inv);
    *reinterpret_cast<ushort2*>(nh + (size_t)row * DIM + lane * 2) = o;
}

// 20 sigma=0.1 Gaussians, incremental quadratic exponent in log2 space;
// exact (mu=1,sigma=1e-3) kernel replaced by integer token equality.
static __device__ __forceinline__ void bank4(float4 pv, int4 dt, int qt, float* ksum) {
    const float mv[4] = {pv.x, pv.y, pv.z, pv.w};
    const int   dv[4] = {dt.x, dt.y, dt.z, dt.w};
#pragma unroll
    for (int i = 0; i < 4; ++i) {
        float m  = mv[i];
        float t0 = m + 0.95f;
        float e0 = (-72.134752f * t0) * t0;              // -50*log2e*t0^2
        float de = fmaf(14.4269504f, t0, -0.72134752f);
#pragma unroll
        for (int k = 0; k < 20; ++k) {
            ksum[k] += EXP2F(e0);
            e0 += de;
            de -= 1.4426950f;
        }
        ksum[20] += (dv[i] == qt) ? 1.0f : 0.0f;         // exact-match kernel
    }
}

// ------------- kernel 2: per-(pair,b) KNRM score -------------
// 1024 blocks x 256 thr (4 waves). MFMA wave = (rt row-16-tile, half col-32).
// Bank thread = (quad = tid>>5 -> cols quad*4 & +32, row = tid&31): padded
// quads make whole waves exec-z on the last tile. LDS ~34 KB -> 4 blocks/CU.
__global__ __launch_bounds__(256) void knrm_main(
    const ushort_t* __restrict__ nh, const float* __restrict__ W,
    const int* __restrict__ q1, const int* __restrict__ d1,
    const int* __restrict__ q2, const int* __restrict__ d2,
    float* __restrict__ logits)
{
    __shared__ int4  sQ[512];      // 32 rows x 16 slots, XOR-swizzled
    __shared__ int4  sD[1024];     // 64 rows x 16 slots, XOR-swizzled
    __shared__ float P[32][68];    // M tile, +4 pad
    __shared__ int   sQtok[32];
    __shared__ int   sDtok[256];
    __shared__ float pbuf[32];

    const int pb = blockIdx.x;
    const int pair = pb >> 9, b = pb & 511;
    const int* qind = (pair ? q2 : q1) + b * LQ;
    const int* dind = (pair ? d2 : d1) + b * RD;
    const int tid = threadIdx.x;
    const int lane = tid & 63, wave = tid >> 6;
    const int r = lane & 15, g = lane >> 4;
    const int rt = wave & 1, half = wave >> 1;

    if (tid < 32) sQtok[tid] = (tid < LQ) ? qind[tid] : -2;
    sDtok[tid] = (tid < RD) ? dind[tid] : -1;

    for (int e = tid; e < 512; e += 256) {          // stage Q (rows>=30 zero)
        int rho = e >> 4, c = e & 15;
        int4 v = {0, 0, 0, 0};
        if (rho < LQ) v = *(const int4*)(nh + (size_t)qind[rho] * DIM + c * 8);
        sQ[rho * 16 + (c ^ (rho & 15))] = v;
    }
    for (int e = tid; e < 1024; e += 256) {         // stage D tile 0
        int rho = e >> 4, c = e & 15;
        int4 v = {0, 0, 0, 0};
        if (rho < RD) v = *(const int4*)(nh + (size_t)dind[rho] * DIM + c * 8);
        sD[rho * 16 + (c ^ (rho & 15))] = v;
    }

    const int qbase  = (rt * 16 + r) * 16;
    const int dbase0 = (half * 32 + r) * 16;
    const int dbase1 = (half * 32 + 16 + r) * 16;
    const int brow = tid & 31;        // bank row
    const int c0   = (tid >> 5) * 4;  // bank quad base col (0..28)

    float ksum[KN];
#pragma unroll
    for (int k = 0; k < KN; ++k) ksum[k] = 0.0f;

    for (int t = 0; t < NT; ++t) {
        const int r0 = t * 64;
        __syncthreads();              // (a) sD(t) staged; bank(t-1)/P reads done

        // ---- MFMA: hi-only bf16, 8 per wave ----
        f32x4 acc0 = {0.f, 0.f, 0.f, 0.f}, acc1 = {0.f, 0.f, 0.f, 0.f};
#pragma unroll
        for (int ks = 0; ks < 4; ++ks) {
            int sl = (4 * ks + g) ^ r;
            bf16x8 ah = as_frag(sQ[qbase + sl]);
            bf16x8 b0 = as_frag(sD[dbase0 + sl]);
            bf16x8 b1 = as_frag(sD[dbase1 + sl]);
            acc0 = __builtin_amdgcn_mfma_f32_16x16x32_bf16(ah, b0, acc0, 0, 0, 0);
            acc1 = __builtin_amdgcn_mfma_f32_16x16x32_bf16(ah, b1, acc1, 0, 0, 0);
        }
        // C/D layout: col = lane&15, row = (lane>>4)*4 + j
#pragma unroll
        for (int j = 0; j < 4; ++j) {
            P[rt * 16 + g * 4 + j][half * 32 + r]      = acc0[j];
            P[rt * 16 + g * 4 + j][half * 32 + 16 + r] = acc1[j];
        }
        __syncthreads();              // (b) P(t) ready; sD(t) consumed

        // ---- T14 async-stage: issue next tile's loads BEFORE the bank ----
        int4 st0 = {0,0,0,0}, st1 = {0,0,0,0}, st2 = {0,0,0,0}, st3 = {0,0,0,0};
        if (t + 1 < NT) {
            const int rb = (t + 1) * 64;
            { int e = tid;       int rho = e >> 4, c = e & 15; if (rb + rho < RD) st0 = *(const int4*)(nh + (size_t)dind[rb + rho] * DIM + c * 8); }
            { int e = tid + 256; int rho = e >> 4, c = e & 15; if (rb + rho < RD) st1 = *(const int4*)(nh + (size_t)dind[rb + rho] * DIM + c * 8); }
            { int e = tid + 512; int rho = e >> 4, c = e & 15; if (rb + rho < RD) st2 = *(const int4*)(nh + (size_t)dind[rb + rho] * DIM + c * 8); }
            { int e = tid + 768; int rho = e >> 4, c = e & 15; if (rb + rho < RD) st3 = *(const int4*)(nh + (size_t)dind[rb + rho] * DIM + c * 8); }
        }

        // ---- bank(t): whole waves exec-z when their quads are padding ----
        if (brow < LQ && r0 + c0 < RD) {             // quads are 4-aligned vs RD=200
            const int qt = sQtok[brow];
            float4 p0 = *reinterpret_cast<const float4*>(&P[brow][c0]);
            int4  dt0 = *reinterpret_cast<const int4*>(&sDtok[r0 + c0]);
            bank4(p0, dt0, qt, ksum);
            if (r0 + c0 + 32 < RD) {
                float4 p1 = *reinterpret_cast<const float4*>(&P[brow][c0 + 32]);
                int4  dt1 = *reinterpret_cast<const int4*>(&sDtok[r0 + c0 + 32]);
                bank4(p1, dt1, qt, ksum);
            }
        }

        // ---- write-late: land the staged tile ----
        if (t + 1 < NT) {
            { int e = tid;       int rho = e >> 4, c = e & 15; sD[rho * 16 + (c ^ (rho & 15))] = st0; }
            { int e = tid + 256; int rho = e >> 4, c = e & 15; sD[rho * 16 + (c ^ (rho & 15))] = st1; }
            { int e = tid + 512; int rho = e >> 4, c = e & 15; sD[rho * 16 + (c ^ (rho & 15))] = st2; }
            { int e = tid + 768; int rho = e >> 4, c = e & 15; sD[rho * 16 + (c ^ (rho & 15))] = st3; }
        }
    }

    __syncthreads();                  // bank(3) done -> sD reusable
    float* kredw = (float*)sD;        // [4 waves][32 rows][21]

#pragma unroll
    for (int k = 0; k < KN; ++k) ksum[k] += __shfl_xor(ksum[k], 32);  // quad pair
    if (lane < 32) {
#pragma unroll
        for (int k = 0; k < KN; ++k)
            kredw[(wave * 32 + lane) * KN + k] = ksum[k];
    }
    __syncthreads();

    if (tid < 32) {
        float part = 0.0f;
        if (tid < LQ) {
#pragma unroll
            for (int k = 0; k < KN; ++k) {
                float s = kredw[tid * KN + k] + kredw[(32 + tid) * KN + k]
                        + kredw[(64 + tid) * KN + k] + kredw[(96 + tid) * KN + k];
                part += W[k] * log1pf(s);
            }
        }
        pbuf[tid] = part;
    }
    __syncthreads();
    if (tid == 0) {
        float logit = 0.0f;
#pragma unroll
        for (int i = 0; i < 32; ++i) logit += pbuf[i];
        logits[pair * BB + b] = logit;   // bias cancels in sigmoid(l1-l2)
    }
}

// ------------- kernel 3: sigmoid of logit difference -------------
__global__ void knrm_final(const float* __restrict__ logits, float* __restrict__ out) {
    int i = blockIdx.x * blockDim.x + threadIdx.x;
    if (i < BB) {
        float x = logits[i] - logits[BB + i];
        out[i] = 1.0f / (1.0f + expf(-x));
    }
}

extern "C" void kernel_launch(void* const* d_in, const int* in_sizes, int n_in,
                              void* d_out, int out_size, void* d_ws, size_t ws_size,
                              hipStream_t stream) {
    const float* emb = (const float*)d_in[0];
    const float* W   = (const float*)d_in[1];
    const int* q1    = (const int*)d_in[3];
    const int* dd1   = (const int*)d_in[4];
    const int* q2    = (const int*)d_in[5];
    const int* dd2   = (const int*)d_in[6];

    ushort_t* nh  = (ushort_t*)d_ws;                 // V*128 bf16 = 12.8 MB
    float* logits = (float*)(nh + (size_t)V * DIM);  // 1024 floats

    knrm_norm<<<V / 4, 256, 0, stream>>>(emb, nh);
    knrm_main<<<1024, 256, 0, stream>>>(nh, W, q1, dd1, q2, dd2, logits);
    knrm_final<<<2, 256, 0, stream>>>(logits, (float*)d_out);
}

// Round 5
// 47.336 us; speedup vs baseline: 6.5050x; 1.3254x over previous
//
#include <hip/hip_runtime.h>
#include <math.h>

#define V   50000
#define DIM 128
#define BB  512
#define LQ  30
#define RD  200
#define KN  21

typedef unsigned short ushort_t;
typedef __attribute__((ext_vector_type(8))) short bf16x8;   // 8 bf16 = 4 VGPRs
typedef __attribute__((ext_vector_type(4))) float f32x4;

#if __has_builtin(__builtin_amdgcn_exp2f)
#define EXP2F(x) __builtin_amdgcn_exp2f(x)
#else
#define EXP2F(x) __expf((x) * 0.69314718f)
#endif

static __device__ __forceinline__ ushort_t f2bf(float x) {
    unsigned u = __builtin_bit_cast(unsigned, x);
    return (ushort_t)((u + 0x7FFFu + ((u >> 16) & 1u)) >> 16);   // RNE
}
static __device__ __forceinline__ bf16x8 as_frag(int4 v) {
    return __builtin_bit_cast(bf16x8, v);
}

// ------------- kernel 1: L2-normalize -> bf16 (hi only), float4 loads -------------
__global__ __launch_bounds__(256) void knrm_norm(const float* __restrict__ emb,
                                                 ushort_t* __restrict__ nh) {
    int row = blockIdx.x * 8 + (threadIdx.x >> 5);   // V = 50000 divisible by 8
    int c4  = (threadIdx.x & 31) * 4;
    const float4 v = *reinterpret_cast<const float4*>(emb + (size_t)row * DIM + c4);
    float ss = v.x * v.x + v.y * v.y + v.z * v.z + v.w * v.w;
#pragma unroll
    for (int off = 1; off < 32; off <<= 1) ss += __shfl_xor(ss, off);
    float inv = 1.0f / fmaxf(sqrtf(ss), 1e-12f);
    uint2 o;
    o.x = (unsigned)f2bf(v.x * inv) | ((unsigned)f2bf(v.y * inv) << 16);
    o.y = (unsigned)f2bf(v.z * inv) | ((unsigned)f2bf(v.w * inv) << 16);
    *reinterpret_cast<uint2*>(nh + (size_t)row * DIM + c4) = o;
}

// 20 sigma=0.1 Gaussians, incremental quadratic exponent in log2 space;
// exact (mu=1,sigma=1e-3) kernel replaced by integer token equality.
static __device__ __forceinline__ void bank4(float4 pv, int4 dt, int qt, float* ksum) {
    const float mv[4] = {pv.x, pv.y, pv.z, pv.w};
    const int   dv[4] = {dt.x, dt.y, dt.z, dt.w};
#pragma unroll
    for (int i = 0; i < 4; ++i) {
        float m  = mv[i];
        float t0 = m + 0.95f;
        float e0 = (-72.134752f * t0) * t0;              // -50*log2e*t0^2
        float de = fmaf(14.4269504f, t0, -0.72134752f);
#pragma unroll
        for (int k = 0; k < 20; ++k) {
            ksum[k] += EXP2F(e0);
            e0 += de;
            de -= 1.4426950f;
        }
        ksum[20] += (dv[i] == qt) ? 1.0f : 0.0f;         // exact-match kernel
    }
}

static __device__ __forceinline__ void load_frag4(const ushort_t* base, int4* f) {
    f[0] = *reinterpret_cast<const int4*>(base);
    f[1] = *reinterpret_cast<const int4*>(base + 32);
    f[2] = *reinterpret_cast<const int4*>(base + 64);
    f[3] = *reinterpret_cast<const int4*>(base + 96);
}

// ------------- kernel 2: gather-direct MFMA + row-serial bank, y-split -------------
// grid (1024 pair*b, 2 col-halves), block 256 = 4 waves.
// y=0: doc cols 0..127 (2 tiles), y=1: cols 128..199. No staging LDS:
// Q frags in regs (gathered once), D frags gathered per tile from L2/L3.
// Bank thread = (row tid&31, quad tid>>5). Partials -> global (plain stores).
__global__ __launch_bounds__(256) void knrm_main(
    const ushort_t* __restrict__ nh,
    const int* __restrict__ q1, const int* __restrict__ d1,
    const int* __restrict__ q2, const int* __restrict__ d2,
    float* __restrict__ partial)
{
    __shared__ __align__(16) char smem[10752];
    float (*P)[68] = reinterpret_cast<float (*)[68]>(smem);   // 32x68 f32 = 8704 B
    float* kredw   = reinterpret_cast<float*>(smem);          // 4x32x21 f32 = 10752 B
    __shared__ int sQtok[32];
    __shared__ int sDtok[128];

    const int pb = blockIdx.x, y = blockIdx.y;
    const int pair = pb >> 9, b = pb & 511;
    const int* qind = (pair ? q2 : q1) + b * LQ;
    const int* dind = (pair ? d2 : d1) + b * RD;
    const int cb = y * 128;

    const int tid = threadIdx.x;
    const int lane = tid & 63, wave = tid >> 6;
    const int r = lane & 15, g = lane >> 4;
    const int rt = wave & 1, half = wave >> 1;

    if (tid < 32)  sQtok[tid] = (tid < LQ) ? qind[tid] : -2;
    if (tid < 128) { int c = cb + tid; sDtok[tid] = (c < RD) ? dind[c] : -1; }

    // ---- Q frags once into regs (rows>=30 dup row 29; masked in bank) ----
    const int qrow = rt * 16 + r;
    const int qi = qind[qrow < LQ ? qrow : LQ - 1];
    int4 qh[4];
    load_frag4(nh + (size_t)qi * DIM + g * 8, qh);

    // D row indices per tile (cols >= RD clamped; masked in bank)
    const int c64_0 = cb, c64_1 = cb + 64;
    const int dr0a = c64_0 + half * 32 + r,  dr0b = dr0a + 16;
    const int dr1a = c64_1 + half * 32 + r,  dr1b = dr1a + 16;
    const int di0a = dind[dr0a < RD ? dr0a : RD - 1];
    const int di0b = dind[dr0b < RD ? dr0b : RD - 1];

    float ksum[KN];
#pragma unroll
    for (int k = 0; k < KN; ++k) ksum[k] = 0.0f;

    const int brow = tid & 31;         // bank row
    const int c0   = (tid >> 5) * 4;   // bank quad base col (0..28)
    const int prow0 = rt * 16 + g * 4;

    // ================== tile 0 ==================
    {
        int4 d0[4], d1[4];
        load_frag4(nh + (size_t)di0a * DIM + g * 8, d0);
        load_frag4(nh + (size_t)di0b * DIM + g * 8, d1);
        f32x4 acc0 = {0.f, 0.f, 0.f, 0.f}, acc1 = {0.f, 0.f, 0.f, 0.f};
#pragma unroll
        for (int ks = 0; ks < 4; ++ks) {
            bf16x8 ah = as_frag(qh[ks]);
            acc0 = __builtin_amdgcn_mfma_f32_16x16x32_bf16(ah, as_frag(d0[ks]), acc0, 0, 0, 0);
            acc1 = __builtin_amdgcn_mfma_f32_16x16x32_bf16(ah, as_frag(d1[ks]), acc1, 0, 0, 0);
        }
        // C/D layout: col = lane&15, row = (lane>>4)*4 + j
#pragma unroll
        for (int j = 0; j < 4; ++j) {
            P[prow0 + j][half * 32 + r]      = acc0[j];
            P[prow0 + j][half * 32 + 16 + r] = acc1[j];
        }
    }
    __syncthreads();                           // P(0) visible

    // ---- T14: issue tile-1 D gathers before bank(0) ----
    int4 e0[4], e1[4];
    {
        const int di1a = dind[dr1a < RD ? dr1a : RD - 1];
        const int di1b = dind[dr1b < RD ? dr1b : RD - 1];
        load_frag4(nh + (size_t)di1a * DIM + g * 8, e0);
        load_frag4(nh + (size_t)di1b * DIM + g * 8, e1);
    }

    // ---- bank(0) ----
    if (brow < LQ && c64_0 + c0 < RD) {
        const int qt = sQtok[brow];
        float4 p0 = *reinterpret_cast<const float4*>(&P[brow][c0]);
        int4  dt0 = *reinterpret_cast<const int4*>(&sDtok[c0]);
        bank4(p0, dt0, qt, ksum);
        if (c64_0 + c0 + 32 < RD) {
            float4 p1 = *reinterpret_cast<const float4*>(&P[brow][c0 + 32]);
            int4  dt1 = *reinterpret_cast<const int4*>(&sDtok[c0 + 32]);
            bank4(p1, dt1, qt, ksum);
        }
    }

    // ================== tile 1 ==================
    f32x4 acc0 = {0.f, 0.f, 0.f, 0.f}, acc1 = {0.f, 0.f, 0.f, 0.f};
#pragma unroll
    for (int ks = 0; ks < 4; ++ks) {
        bf16x8 ah = as_frag(qh[ks]);
        acc0 = __builtin_amdgcn_mfma_f32_16x16x32_bf16(ah, as_frag(e0[ks]), acc0, 0, 0, 0);
        acc1 = __builtin_amdgcn_mfma_f32_16x16x32_bf16(ah, as_frag(e1[ks]), acc1, 0, 0, 0);
    }
    __syncthreads();                           // bank(0) P reads done everywhere
#pragma unroll
    for (int j = 0; j < 4; ++j) {
        P[prow0 + j][half * 32 + r]      = acc0[j];
        P[prow0 + j][half * 32 + 16 + r] = acc1[j];
    }
    __syncthreads();                           // P(1) visible

    if (brow < LQ && c64_1 + c0 < RD) {
        const int qt = sQtok[brow];
        float4 p0 = *reinterpret_cast<const float4*>(&P[brow][c0]);
        int4  dt0 = *reinterpret_cast<const int4*>(&sDtok[64 + c0]);
        bank4(p0, dt0, qt, ksum);
        if (c64_1 + c0 + 32 < RD) {
            float4 p1 = *reinterpret_cast<const float4*>(&P[brow][c0 + 32]);
            int4  dt1 = *reinterpret_cast<const int4*>(&sDtok[64 + c0 + 32]);
            bank4(p1, dt1, qt, ksum);
        }
    }
    __syncthreads();                           // P dead -> smem reusable as kredw

    // ---- reduce: quad-pairs via xor32, cross-wave via LDS ----
#pragma unroll
    for (int k = 0; k < KN; ++k) ksum[k] += __shfl_xor(ksum[k], 32);
    if (lane < 32) {
#pragma unroll
        for (int k = 0; k < KN; ++k)
            kredw[(wave * 32 + lane) * KN + k] = ksum[k];
    }
    __syncthreads();

    float* dst = partial + ((size_t)pb * 2 + y) * (LQ * KN);
    for (int e = tid; e < LQ * KN; e += 256) {
        int row = e / KN, k = e - row * KN;
        dst[e] = kredw[row * KN + k] + kredw[(32 + row) * KN + k]
               + kredw[(64 + row) * KN + k] + kredw[(96 + row) * KN + k];
    }
}

// ------------- kernel 3: combine halves, log1p, W-dot, diff, sigmoid -------------
__global__ __launch_bounds__(128) void knrm_finish(const float* __restrict__ partial,
                                                   const float* __restrict__ W,
                                                   float* __restrict__ out) {
    __shared__ float red[2];
    const int b = blockIdx.x, tid = threadIdx.x;
    float s = 0.0f;
    for (int e = tid; e < LQ * KN; e += 128) {
        int row = e / KN, k = e - row * KN;
        float s1 = partial[((size_t)b * 2 + 0) * (LQ * KN) + e]
                 + partial[((size_t)b * 2 + 1) * (LQ * KN) + e];
        float s2 = partial[((size_t)(BB + b) * 2 + 0) * (LQ * KN) + e]
                 + partial[((size_t)(BB + b) * 2 + 1) * (LQ * KN) + e];
        s += W[k] * (log1pf(s1) - log1pf(s2));
    }
#pragma unroll
    for (int off = 1; off < 64; off <<= 1) s += __shfl_xor(s, off);
    if ((tid & 63) == 0) red[tid >> 6] = s;
    __syncthreads();
    if (tid == 0) {
        float logit = red[0] + red[1];   // bias cancels in the difference
        out[b] = 1.0f / (1.0f + expf(-logit));
    }
}

extern "C" void kernel_launch(void* const* d_in, const int* in_sizes, int n_in,
                              void* d_out, int out_size, void* d_ws, size_t ws_size,
                              hipStream_t stream) {
    const float* emb = (const float*)d_in[0];
    const float* W   = (const float*)d_in[1];
    const int* q1    = (const int*)d_in[3];
    const int* dd1   = (const int*)d_in[4];
    const int* q2    = (const int*)d_in[5];
    const int* dd2   = (const int*)d_in[6];

    float* partial = (float*)d_ws;                          // 2048*630 f32 = 5.16 MB
    ushort_t* nh   = (ushort_t*)(partial + 2048 * LQ * KN); // V*128 bf16 = 12.8 MB

    knrm_norm<<<V / 8, 256, 0, stream>>>(emb, nh);
    dim3 grid(1024, 2);
    knrm_main<<<grid, 256, 0, stream>>>(nh, q1, dd1, q2, dd2, partial);
    knrm_finish<<<BB, 128, 0, stream>>>(partial, W, (float*)d_out);
}

// Round 6
// 41.708 us; speedup vs baseline: 7.3827x; 1.1349x over previous
//
#include <hip/hip_runtime.h>
#include <math.h>

#define V   50000
#define DIM 128
#define BB  512
#define LQ  30
#define RD  200
#define KN  21

typedef unsigned short ushort_t;
typedef __attribute__((ext_vector_type(8))) short bf16x8;   // 8 bf16 = 4 VGPRs
typedef __attribute__((ext_vector_type(4))) float f32x4;

#if __has_builtin(__builtin_amdgcn_exp2f)
#define EXP2F(x) __builtin_amdgcn_exp2f(x)
#else
#define EXP2F(x) __expf((x) * 0.69314718f)
#endif

#define ALPHA 72.1347520f       // 50 * log2(e)
#define E10   22026.4657948f    // 2^(0.2*ALPHA) = e^10

static __device__ __forceinline__ ushort_t f2bf(float x) {
    unsigned u = __builtin_bit_cast(unsigned, x);
    return (ushort_t)((u + 0x7FFFu + ((u >> 16) & 1u)) >> 16);   // RNE
}
static __device__ __forceinline__ bf16x8 as_frag(int4 v) {
    return __builtin_bit_cast(bf16x8, v);
}

// ------------- kernel 1: L2-normalize -> bf16 (hi only), float4 loads -------------
__global__ __launch_bounds__(256) void knrm_norm(const float* __restrict__ emb,
                                                 ushort_t* __restrict__ nh) {
    int row = blockIdx.x * 8 + (threadIdx.x >> 5);   // V divisible by 8
    int c4  = (threadIdx.x & 31) * 4;
    const float4 v = *reinterpret_cast<const float4*>(emb + (size_t)row * DIM + c4);
    float ss = v.x * v.x + v.y * v.y + v.z * v.z + v.w * v.w;
#pragma unroll
    for (int off = 1; off < 32; off <<= 1) ss += __shfl_xor(ss, off);
    float inv = 1.0f / fmaxf(sqrtf(ss), 1e-12f);
    uint2 o;
    o.x = (unsigned)f2bf(v.x * inv) | ((unsigned)f2bf(v.y * inv) << 16);
    o.y = (unsigned)f2bf(v.z * inv) | ((unsigned)f2bf(v.w * inv) << 16);
    *reinterpret_cast<uint2*>(nh + (size_t)row * DIM + c4) = o;
}

// Two-leg geometric Gaussian bank: K_k(m) = B_j * t_j, t_{j+1} = t_j * u.
// Leg A: kernels 0..9 (center mu=-0.5), leg B: 10..19 (center mu=+0.5).
// B_j = 2^(-0.01*ALPHA*j^2), j = (k%10) - 4.5, applied at the store stage.
// Exact kernel (mu=1, sigma=1e-3) = integer token equality count.
static __device__ __forceinline__ void bank4_geo(float4 pv, int4 dt, int qt,
                                                 float* accA, float* accB, float& cnt) {
    const float mv[4] = {pv.x, pv.y, pv.z, pv.w};
    const int   dv[4] = {dt.x, dt.y, dt.z, dt.w};
#pragma unroll
    for (int i = 0; i < 4; ++i) {
        float m  = mv[i];
        float dA = m + 0.5f, dB = m - 0.5f;
        float tA = EXP2F(-ALPHA * dA * (dA + 0.9f));   // t at j=-4.5 (k=0)
        float tB = EXP2F(-ALPHA * dB * (dB + 0.9f));   // t at j=-4.5 (k=10)
        float uB = EXP2F(14.4269504f * dB);            // 2^(0.2*ALPHA*dB)
        float uA = uB * E10;                           // 2^(0.2*ALPHA*dA)
        cnt += (dv[i] == qt) ? 1.0f : 0.0f;
#pragma unroll
        for (int k = 0; k < 10; ++k) {
            accA[k] += tA; tA *= uA;
            accB[k] += tB; tB *= uB;
        }
    }
}

static __device__ __forceinline__ void load_frag4(const ushort_t* base, int4* f) {
    f[0] = *reinterpret_cast<const int4*>(base);
    f[1] = *reinterpret_cast<const int4*>(base + 32);
    f[2] = *reinterpret_cast<const int4*>(base + 64);
    f[3] = *reinterpret_cast<const int4*>(base + 96);
}

// ------------- kernel 2: gather-direct MFMA + geometric bank, y-split -------------
__global__ __launch_bounds__(256) void knrm_main(
    const ushort_t* __restrict__ nh,
    const int* __restrict__ q1, const int* __restrict__ d1,
    const int* __restrict__ q2, const int* __restrict__ d2,
    float* __restrict__ partial)
{
    __shared__ __align__(16) char smem[10752];
    float (*P)[68] = reinterpret_cast<float (*)[68]>(smem);   // 32x68 f32
    float* kredw   = reinterpret_cast<float*>(smem);          // 4x32x21 f32
    __shared__ int sQtok[32];
    __shared__ int sDtok[128];

    const int pb = blockIdx.x, y = blockIdx.y;
    const int pair = pb >> 9, b = pb & 511;
    const int* qind = (pair ? q2 : q1) + b * LQ;
    const int* dind = (pair ? d2 : d1) + b * RD;
    const int cb = y * 128;

    const int tid = threadIdx.x;
    const int lane = tid & 63, wave = tid >> 6;
    const int r = lane & 15, g = lane >> 4;
    const int rt = wave & 1, half = wave >> 1;

    if (tid < 32)  sQtok[tid] = (tid < LQ) ? qind[tid] : -2;
    if (tid < 128) { int c = cb + tid; sDtok[tid] = (c < RD) ? dind[c] : -1; }

    // ---- Q frags once into regs ----
    const int qrow = rt * 16 + r;
    const int qi = qind[qrow < LQ ? qrow : LQ - 1];
    int4 qh[4];
    load_frag4(nh + (size_t)qi * DIM + g * 8, qh);

    const int c64_0 = cb, c64_1 = cb + 64;
    const int dr0a = c64_0 + half * 32 + r,  dr0b = dr0a + 16;
    const int dr1a = c64_1 + half * 32 + r,  dr1b = dr1a + 16;
    const int di0a = dind[dr0a < RD ? dr0a : RD - 1];
    const int di0b = dind[dr0b < RD ? dr0b : RD - 1];

    float ksum[KN];   // [0..9]=legA, [10..19]=legB, [20]=exact count
#pragma unroll
    for (int k = 0; k < KN; ++k) ksum[k] = 0.0f;

    const int brow = tid & 31;         // bank row
    const int c0   = (tid >> 5) * 4;   // bank quad base col (0..28)
    const int prow0 = rt * 16 + g * 4;

    // ================== tile 0 ==================
    {
        int4 d0[4], d1[4];
        load_frag4(nh + (size_t)di0a * DIM + g * 8, d0);
        load_frag4(nh + (size_t)di0b * DIM + g * 8, d1);
        f32x4 acc0 = {0.f, 0.f, 0.f, 0.f}, acc1 = {0.f, 0.f, 0.f, 0.f};
#pragma unroll
        for (int ks = 0; ks < 4; ++ks) {
            bf16x8 ah = as_frag(qh[ks]);
            acc0 = __builtin_amdgcn_mfma_f32_16x16x32_bf16(ah, as_frag(d0[ks]), acc0, 0, 0, 0);
            acc1 = __builtin_amdgcn_mfma_f32_16x16x32_bf16(ah, as_frag(d1[ks]), acc1, 0, 0, 0);
        }
        // C/D layout: col = lane&15, row = (lane>>4)*4 + j
#pragma unroll
        for (int j = 0; j < 4; ++j) {
            P[prow0 + j][half * 32 + r]      = acc0[j];
            P[prow0 + j][half * 32 + 16 + r] = acc1[j];
        }
    }
    __syncthreads();                           // P(0) visible

    // ---- T14: issue tile-1 D gathers before bank(0) ----
    int4 e0[4], e1[4];
    {
        const int di1a = dind[dr1a < RD ? dr1a : RD - 1];
        const int di1b = dind[dr1b < RD ? dr1b : RD - 1];
        load_frag4(nh + (size_t)di1a * DIM + g * 8, e0);
        load_frag4(nh + (size_t)di1b * DIM + g * 8, e1);
    }

    // ---- bank(0) ----
    if (brow < LQ && c64_0 + c0 < RD) {
        const int qt = sQtok[brow];
        float4 p0 = *reinterpret_cast<const float4*>(&P[brow][c0]);
        int4  dt0 = *reinterpret_cast<const int4*>(&sDtok[c0]);
        bank4_geo(p0, dt0, qt, ksum, ksum + 10, ksum[20]);
        if (c64_0 + c0 + 32 < RD) {
            float4 p1 = *reinterpret_cast<const float4*>(&P[brow][c0 + 32]);
            int4  dt1 = *reinterpret_cast<const int4*>(&sDtok[c0 + 32]);
            bank4_geo(p1, dt1, qt, ksum, ksum + 10, ksum[20]);
        }
    }

    // ================== tile 1 ==================
    f32x4 acc0 = {0.f, 0.f, 0.f, 0.f}, acc1 = {0.f, 0.f, 0.f, 0.f};
#pragma unroll
    for (int ks = 0; ks < 4; ++ks) {
        bf16x8 ah = as_frag(qh[ks]);
        acc0 = __builtin_amdgcn_mfma_f32_16x16x32_bf16(ah, as_frag(e0[ks]), acc0, 0, 0, 0);
        acc1 = __builtin_amdgcn_mfma_f32_16x16x32_bf16(ah, as_frag(e1[ks]), acc1, 0, 0, 0);
    }
    __syncthreads();                           // bank(0) P reads done
#pragma unroll
    for (int j = 0; j < 4; ++j) {
        P[prow0 + j][half * 32 + r]      = acc0[j];
        P[prow0 + j][half * 32 + 16 + r] = acc1[j];
    }
    __syncthreads();                           // P(1) visible

    if (brow < LQ && c64_1 + c0 < RD) {
        const int qt = sQtok[brow];
        float4 p0 = *reinterpret_cast<const float4*>(&P[brow][c0]);
        int4  dt0 = *reinterpret_cast<const int4*>(&sDtok[64 + c0]);
        bank4_geo(p0, dt0, qt, ksum, ksum + 10, ksum[20]);
        if (c64_1 + c0 + 32 < RD) {
            float4 p1 = *reinterpret_cast<const float4*>(&P[brow][c0 + 32]);
            int4  dt1 = *reinterpret_cast<const int4*>(&sDtok[64 + c0 + 32]);
            bank4_geo(p1, dt1, qt, ksum, ksum + 10, ksum[20]);
        }
    }
    __syncthreads();                           // P dead -> smem = kredw

    // ---- reduce: quad-pairs via xor32, cross-wave via LDS ----
#pragma unroll
    for (int k = 0; k < KN; ++k) ksum[k] += __shfl_xor(ksum[k], 32);
    if (lane < 32) {
#pragma unroll
        for (int k = 0; k < KN; ++k)
            kredw[(wave * 32 + lane) * KN + k] = ksum[k];
    }
    __syncthreads();

    // store partials, folding in the per-kernel B_j constant
    float* dst = partial + ((size_t)pb * 2 + y) * (LQ * KN);
    for (int e = tid; e < LQ * KN; e += 256) {
        int row = e / KN, k = e - row * KN;
        float s = kredw[row * KN + k] + kredw[(32 + row) * KN + k]
                + kredw[(64 + row) * KN + k] + kredw[(96 + row) * KN + k];
        float sc = 1.0f;
        if (k < 20) {
            float j = (float)((k < 10) ? k : k - 10) - 4.5f;
            sc = EXP2F(-0.721347520f * j * j);     // B_j = 2^(-0.01*ALPHA*j^2)
        }
        dst[e] = sc * s;
    }
}

// ------------- kernel 3: combine halves, log1p, W-dot, diff, sigmoid -------------
__global__ __launch_bounds__(128) void knrm_finish(const float* __restrict__ partial,
                                                   const float* __restrict__ W,
                                                   float* __restrict__ out) {
    __shared__ float red[2];
    const int b = blockIdx.x, tid = threadIdx.x;
    float s = 0.0f;
    for (int e = tid; e < LQ * KN; e += 128) {
        int row = e / KN, k = e - row * KN;
        float s1 = partial[((size_t)b * 2 + 0) * (LQ * KN) + e]
                 + partial[((size_t)b * 2 + 1) * (LQ * KN) + e];
        float s2 = partial[((size_t)(BB + b) * 2 + 0) * (LQ * KN) + e]
                 + partial[((size_t)(BB + b) * 2 + 1) * (LQ * KN) + e];
        s += W[k] * (log1pf(s1) - log1pf(s2));
    }
#pragma unroll
    for (int off = 1; off < 64; off <<= 1) s += __shfl_xor(s, off);
    if ((tid & 63) == 0) red[tid >> 6] = s;
    __syncthreads();
    if (tid == 0) {
        float logit = red[0] + red[1];   // bias cancels in the difference
        out[b] = 1.0f / (1.0f + expf(-logit));
    }
}

extern "C" void kernel_launch(void* const* d_in, const int* in_sizes, int n_in,
                              void* d_out, int out_size, void* d_ws, size_t ws_size,
                              hipStream_t stream) {
    const float* emb = (const float*)d_in[0];
    const float* W   = (const float*)d_in[1];
    const int* q1    = (const int*)d_in[3];
    const int* dd1   = (const int*)d_in[4];
    const int* q2    = (const int*)d_in[5];
    const int* dd2   = (const int*)d_in[6];

    float* partial = (float*)d_ws;                          // 2048*630 f32 = 5.16 MB
    ushort_t* nh   = (ushort_t*)(partial + 2048 * LQ * KN); // V*128 bf16 = 12.8 MB

    knrm_norm<<<V / 8, 256, 0, stream>>>(emb, nh);
    dim3 grid(1024, 2);
    knrm_main<<<grid, 256, 0, stream>>>(nh, q1, dd1, q2, dd2, partial);
    knrm_finish<<<BB, 128, 0, stream>>>(partial, W, (float*)d_out);
}